// Round 13
// baseline (25.592 us; speedup 1.0000x reference)
//
#include <hip/hip_runtime.h>

#define C_IN   256
#define C_OUT  128
#define H_DIM  270
#define W_DIM  480
#define N_PTS  512
#define K_CLS  5

#define PB     16                 // points per conv block (M-tile)
#define CC     8                  // K-chunks; K per chunk = 288 = 9*32
#define CI_PER (C_IN / CC)        // 32 ci per chunk
#define TERMS  (CI_PER * 9)       // 288 K-terms, contiguous in conv_w per co
#define KSTEPS (TERMS / 32)       // 9 MFMA K-steps
#define JOBS   (PB * CI_PER * 3)  // 1536 patch row-jobs (= 6 per thread exactly)
#define PTG_N  (N_PTS / PB)       // 32 point groups

using f32x4 = __attribute__((ext_vector_type(4))) float;
using s16x8 = __attribute__((ext_vector_type(8))) short;
typedef float float4a __attribute__((ext_vector_type(4), aligned(4)));

// round-to-nearest-even f32 -> bf16
__device__ __forceinline__ unsigned short f2bf(float f) {
    unsigned u = __float_as_uint(f);
    return (unsigned short)((u + 0x7FFFu + ((u >> 16) & 1u)) >> 16);
}

// ---------------------------------------------------------------------------
// Kernel 1: MFMA gather-conv (R11 champion structure).
// One block per (ptg, chunk): M=16 pts, N=128 co, K=288. 4 waves x 2
// col-tiles. A (patch): one dwordx4 per row-job (covers cx-1..cx+2, same
// cache lines as 3 dwords, 3x fewer VMEM issues) -> bf16 -> LDS A-frag
// layout. B (weights): per-lane contiguous -> bf16 regs. fp32 accumulate.
// Block 0 also zeroes loss_out for the head's atomic reduction.
// Layouts (R11-verified): A row=l&15, k=(l>>4)*8+j; B col=l&15;
// D row=(l>>4)*4+reg, col=l&15.
// ---------------------------------------------------------------------------
__global__ __launch_bounds__(256) void gemm_conv(
        const float* __restrict__ bb,       // [C_IN][H][W]
        const int*   __restrict__ centers,  // [N][2] (x, y)
        const float* __restrict__ conv_w,   // [co][ci][3][3]
        float*       __restrict__ part,     // [CC][N_PTS][C_OUT]
        float*       __restrict__ loss_out) // [1]
{
    __shared__ unsigned short pa[KSTEPS * 64 * 8];   // 9216 B, A-frag layout

    const int chunk = blockIdx.x & (CC - 1);
    const int ptg   = blockIdx.x >> 3;      // 0..31
    const int t     = threadIdx.x;
    const int l     = t & 63;
    const int w     = t >> 6;               // wave id: col-tiles {2w, 2w+1}
    const int c     = l & 15;
    const int hi    = l >> 4;

    if (blockIdx.x == 0 && t == 0) loss_out[0] = 0.f;

    // --- issue scattered patch loads (one dwordx4 per row-job) ---
    float pvv[6][3];
    #pragma unroll
    for (int jj = 0; jj < 6; ++jj) {
        const int i   = t + jj * 256;       // 0..1535, exact
        const int pt  = i & 15;
        const int rem = i >> 4;             // 0..95
        const int lci = rem / 3;
        const int dy  = rem - lci * 3;
        const int n   = ptg * PB + pt;
        const int cx  = centers[2 * n];     // [0,270); cx+2 <= 271 < 480
        const int cy  = centers[2 * n + 1];
        const int y   = cy + dy - 1;
        pvv[jj][0] = pvv[jj][1] = pvv[jj][2] = 0.f;
        if (y >= 0 && y < H_DIM) {
            const float* row = bb +
                ((size_t)(chunk * CI_PER + lci) * H_DIM + y) * W_DIM;
            if (cx >= 1) {
                const float4a f = *(const float4a*)(row + cx - 1);
                pvv[jj][0] = f.x; pvv[jj][1] = f.y; pvv[jj][2] = f.z;
            } else {
                pvv[jj][1] = row[0];
                pvv[jj][2] = row[1];
            }
        }
    }

    // --- B operand: per-lane contiguous weight runs -> bf16 frags ---
    s16x8 bfrag[2][KSTEPS];
    #pragma unroll
    for (int ct = 0; ct < 2; ++ct) {
        const int co = (2 * w + ct) * 16 + c;
        const float* base = conv_w + (size_t)co * (C_IN * 9)
                                   + chunk * TERMS + hi * 8;
        #pragma unroll
        for (int ks = 0; ks < KSTEPS; ++ks) {
            const float4a lo = *(const float4a*)(base + ks * 32);
            const float4a hh = *(const float4a*)(base + ks * 32 + 4);
            s16x8 v;
            v[0] = (short)f2bf(lo.x); v[1] = (short)f2bf(lo.y);
            v[2] = (short)f2bf(lo.z); v[3] = (short)f2bf(lo.w);
            v[4] = (short)f2bf(hh.x); v[5] = (short)f2bf(hh.y);
            v[6] = (short)f2bf(hh.z); v[7] = (short)f2bf(hh.w);
            bfrag[ct][ks] = v;
        }
    }

    // --- drain patch to LDS in A-fragment layout (bf16) ---
    #pragma unroll
    for (int jj = 0; jj < 6; ++jj) {
        const int i   = t + jj * 256;
        const int pt  = i & 15;
        const int rem = i >> 4;
        const int lci = rem / 3;
        const int dy  = rem - lci * 3;
        #pragma unroll
        for (int dx = 0; dx < 3; ++dx) {
            const int K  = lci * 9 + dy * 3 + dx;
            const int ks = K >> 5, r = K & 31;
            pa[(ks * 64 + (r >> 3) * 16 + pt) * 8 + (r & 7)] =
                f2bf(pvv[jj][dx]);
        }
    }
    __syncthreads();

    // --- MFMA loop: 9 ksteps x 2 col-tiles ---
    f32x4 acc0 = {0.f, 0.f, 0.f, 0.f};
    f32x4 acc1 = {0.f, 0.f, 0.f, 0.f};
    #pragma unroll
    for (int ks = 0; ks < KSTEPS; ++ks) {
        const s16x8 a = *(const s16x8*)&pa[(ks * 64 + l) * 8];  // lane-linear
        acc0 = __builtin_amdgcn_mfma_f32_16x16x32_bf16(a, bfrag[0][ks], acc0, 0, 0, 0);
        acc1 = __builtin_amdgcn_mfma_f32_16x16x32_bf16(a, bfrag[1][ks], acc1, 0, 0, 0);
    }

    // --- store D: row=(l>>4)*4+reg, col=l&15; 64B-coalesced over lanes ---
    #pragma unroll
    for (int reg = 0; reg < 4; ++reg) {
        const int n = ptg * PB + hi * 4 + reg;
        float* pr = part + ((size_t)chunk * N_PTS + n) * C_OUT;
        pr[(2 * w + 0) * 16 + c] = acc0[reg];
        pr[(2 * w + 1) * 16 + c] = acc1[reg];
    }
}

// ---------------------------------------------------------------------------
// Kernel 2: head + atomic loss reduction. One wave per point. Lane owns
// co-pair (2l, 2l+1): float2 chunk-sum (fixed order), bias+relu,
// logits/softmax/P/NLL. Loss: single relaxed device-scope atomicAdd per
// point to loss_out (zeroed by gemm_conv) -- no fence, no extra dispatch.
// ---------------------------------------------------------------------------
__global__ __launch_bounds__(64) void head_kernel(
        const float* __restrict__ part,   // [CC][N_PTS][C_OUT]
        const float* __restrict__ conv_b, // [C_OUT]
        const float* __restrict__ fc_w,   // [K][C_OUT]
        const float* __restrict__ fc_b,   // [K]
        const float* __restrict__ L,      // [N][K]
        float*       __restrict__ P,      // [N][K]
        float*       __restrict__ loss_out) // [1]
{
    const int n    = blockIdx.x;
    const int lane = threadIdx.x;

    const float* pc = part + (size_t)n * C_OUT + 2 * lane;
    float vx = 0.f, vy = 0.f;
    #pragma unroll
    for (int cidx = 0; cidx < CC; ++cidx) {
        const float2 pp = *(const float2*)(pc + (size_t)cidx * N_PTS * C_OUT);
        vx += pp.x; vy += pp.y;
    }
    const float2 cb = *(const float2*)&conv_b[2 * lane];
    vx = fmaxf(vx + cb.x, 0.f);
    vy = fmaxf(vy + cb.y, 0.f);

    float logit[K_CLS];
    #pragma unroll
    for (int k = 0; k < K_CLS; ++k) {
        const float2 wv = *(const float2*)&fc_w[k * C_OUT + 2 * lane];
        float p = vx * wv.x + vy * wv.y;
        #pragma unroll
        for (int off = 32; off > 0; off >>= 1)
            p += __shfl_xor(p, off, 64);
        logit[k] = p + fc_b[k];
    }

    if (lane == 0) {
        float m = logit[0];
        #pragma unroll
        for (int k = 1; k < K_CLS; ++k) m = fmaxf(m, logit[k]);
        float e[K_CLS];
        float s = 0.f;
        #pragma unroll
        for (int k = 0; k < K_CLS; ++k) { e[k] = expf(logit[k] - m); s += e[k]; }
        const float inv  = 1.f / s;
        const float logs = logf(s);
        float lp = 0.f;
        #pragma unroll
        for (int k = 0; k < K_CLS; ++k) {
            P[n * K_CLS + k] = e[k] * inv;
            lp -= L[n * K_CLS + k] * ((logit[k] - m) - logs);
        }
        atomicAdd(loss_out, lp);           // device-scope, relaxed, no fence
    }
}

// ---------------------------------------------------------------------------
extern "C" void kernel_launch(void* const* d_in, const int* in_sizes, int n_in,
                              void* d_out, int out_size, void* d_ws, size_t ws_size,
                              hipStream_t stream) {
    const float* bb      = (const float*)d_in[0];   // backbone_map
    const int*   centers = (const int*)  d_in[1];
    const float* L       = (const float*)d_in[2];
    const float* conv_w  = (const float*)d_in[3];
    const float* conv_b  = (const float*)d_in[4];
    const float* fc_w    = (const float*)d_in[5];
    const float* fc_b    = (const float*)d_in[6];

    float* out      = (float*)d_out;            // P: [0, 2560)
    float* loss_out = (float*)d_out + N_PTS * K_CLS;

    // workspace (floats): part 8*512*128 (2.1 MB)
    float* part = (float*)d_ws;

    gemm_conv<<<PTG_N * CC, 256, 0, stream>>>(bb, centers, conv_w, part,
                                              loss_out);
    head_kernel<<<N_PTS, 64, 0, stream>>>(part, conv_b, fc_w, fc_b, L, out,
                                          loss_out);
}

// Round 14
// 21.178 us; speedup vs baseline: 1.2084x; 1.2084x over previous
//
#include <hip/hip_runtime.h>

#define C_IN   256
#define C_OUT  128
#define H_DIM  270
#define W_DIM  480
#define N_PTS  512
#define K_CLS  5

#define PB     16                 // points per conv block (M-tile)
#define CC     8                  // K-chunks; K per chunk = 288 = 9*32
#define CI_PER (C_IN / CC)        // 32 ci per chunk
#define TERMS  (CI_PER * 9)       // 288 K-terms, contiguous in conv_w per co
#define KSTEPS (TERMS / 32)       // 9 MFMA K-steps
#define JOBS   (PB * CI_PER * 3)  // 1536 patch row-jobs (= 6 per thread exactly)
#define PTG_N  (N_PTS / PB)       // 32 point groups

using f32x4 = __attribute__((ext_vector_type(4))) float;
using s16x8 = __attribute__((ext_vector_type(8))) short;

// round-to-nearest-even f32 -> bf16
__device__ __forceinline__ unsigned short f2bf(float f) {
    unsigned u = __float_as_uint(f);
    return (unsigned short)((u + 0x7FFFu + ((u >> 16) & 1u)) >> 16);
}

// ---------------------------------------------------------------------------
// Kernel 1: MFMA gather-conv (R11 champion, restored verbatim).
// One block per (ptg, chunk): M=16 pts, N=128 co, K=288. 4 waves x 2
// col-tiles (16 co each). A (patch) gathered scattered (3 dword loads per
// row-job, single-sided edge guard) -> bf16 -> LDS in A-fragment layout
// (lane-linear b128 reads, conflict-free). B (weights) per-lane contiguous
// -> bf16 regs (4-lane 128B coalesced). 18 MFMA per wave; fp32 accumulate.
// Layouts (verified): A row=l&15, k=(l>>4)*8+j; B col=l&15, same k;
// D row=(l>>4)*4+reg, col=l&15.
// ---------------------------------------------------------------------------
__global__ __launch_bounds__(256) void gemm_conv(
        const float* __restrict__ bb,       // [C_IN][H][W]
        const int*   __restrict__ centers,  // [N][2] (x, y)
        const float* __restrict__ conv_w,   // [co][ci][3][3]
        float*       __restrict__ part)     // [CC][N_PTS][C_OUT]
{
    __shared__ unsigned short pa[KSTEPS * 64 * 8];   // 9216 B, A-frag layout

    const int chunk = blockIdx.x & (CC - 1);
    const int ptg   = blockIdx.x >> 3;      // 0..31
    const int t     = threadIdx.x;
    const int l     = t & 63;
    const int w     = t >> 6;               // wave id: col-tiles {2w, 2w+1}
    const int c     = l & 15;
    const int hi    = l >> 4;

    // --- issue scattered patch loads into registers (6 row-jobs/thread) ---
    float pvv[6][3];
    #pragma unroll
    for (int jj = 0; jj < 6; ++jj) {
        const int i   = t + jj * 256;       // 0..1535, exact
        const int pt  = i & 15;
        const int rem = i >> 4;             // 0..95
        const int lci = rem / 3;
        const int dy  = rem - lci * 3;
        const int n   = ptg * PB + pt;
        const int cx  = centers[2 * n];     // [0,270); cx+1 < 480 always
        const int cy  = centers[2 * n + 1];
        const int y   = cy + dy - 1;
        pvv[jj][0] = pvv[jj][1] = pvv[jj][2] = 0.f;
        if (y >= 0 && y < H_DIM) {
            const float* row = bb +
                ((size_t)(chunk * CI_PER + lci) * H_DIM + y) * W_DIM + cx;
            pvv[jj][1] = row[0];
            pvv[jj][2] = row[1];
            if (cx >= 1) pvv[jj][0] = row[-1];
        }
    }

    // --- B operand: per-lane contiguous weight runs -> bf16 frags ---
    s16x8 bfrag[2][KSTEPS];
    #pragma unroll
    for (int ct = 0; ct < 2; ++ct) {
        const int co = (2 * w + ct) * 16 + c;
        const float* base = conv_w + (size_t)co * (C_IN * 9)
                                   + chunk * TERMS + hi * 8;
        #pragma unroll
        for (int ks = 0; ks < KSTEPS; ++ks) {
            const float4 lo = *(const float4*)(base + ks * 32);
            const float4 hh = *(const float4*)(base + ks * 32 + 4);
            s16x8 v;
            v[0] = (short)f2bf(lo.x); v[1] = (short)f2bf(lo.y);
            v[2] = (short)f2bf(lo.z); v[3] = (short)f2bf(lo.w);
            v[4] = (short)f2bf(hh.x); v[5] = (short)f2bf(hh.y);
            v[6] = (short)f2bf(hh.z); v[7] = (short)f2bf(hh.w);
            bfrag[ct][ks] = v;
        }
    }

    // --- drain patch to LDS in A-fragment layout (bf16) ---
    #pragma unroll
    for (int jj = 0; jj < 6; ++jj) {
        const int i   = t + jj * 256;
        const int pt  = i & 15;
        const int rem = i >> 4;
        const int lci = rem / 3;
        const int dy  = rem - lci * 3;
        #pragma unroll
        for (int dx = 0; dx < 3; ++dx) {
            const int K  = lci * 9 + dy * 3 + dx;
            const int ks = K >> 5, r = K & 31;
            pa[(ks * 64 + (r >> 3) * 16 + pt) * 8 + (r & 7)] =
                f2bf(pvv[jj][dx]);
        }
    }
    __syncthreads();

    // --- MFMA loop: 9 ksteps x 2 col-tiles ---
    f32x4 acc0 = {0.f, 0.f, 0.f, 0.f};
    f32x4 acc1 = {0.f, 0.f, 0.f, 0.f};
    #pragma unroll
    for (int ks = 0; ks < KSTEPS; ++ks) {
        const s16x8 a = *(const s16x8*)&pa[(ks * 64 + l) * 8];  // lane-linear
        acc0 = __builtin_amdgcn_mfma_f32_16x16x32_bf16(a, bfrag[0][ks], acc0, 0, 0, 0);
        acc1 = __builtin_amdgcn_mfma_f32_16x16x32_bf16(a, bfrag[1][ks], acc1, 0, 0, 0);
    }

    // --- store D: row=(l>>4)*4+reg, col=l&15; 64B-coalesced over lanes ---
    #pragma unroll
    for (int reg = 0; reg < 4; ++reg) {
        const int n = ptg * PB + hi * 4 + reg;
        float* pr = part + ((size_t)chunk * N_PTS + n) * C_OUT;
        pr[(2 * w + 0) * 16 + c] = acc0[reg];
        pr[(2 * w + 1) * 16 + c] = acc1[reg];
    }
}

// ---------------------------------------------------------------------------
// Kernel 2: head. One wave per point. Lane owns co-pair (2l, 2l+1): float2
// chunk-sum (fixed order -> deterministic), bias+relu, logits/softmax/P/NLL.
// ---------------------------------------------------------------------------
__global__ __launch_bounds__(64) void head_kernel(
        const float* __restrict__ part,   // [CC][N_PTS][C_OUT]
        const float* __restrict__ conv_b, // [C_OUT]
        const float* __restrict__ fc_w,   // [K][C_OUT]
        const float* __restrict__ fc_b,   // [K]
        const float* __restrict__ L,      // [N][K]
        float*       __restrict__ P,      // [N][K]
        float*       __restrict__ loss_part) // [N]
{
    const int n    = blockIdx.x;
    const int lane = threadIdx.x;

    const float* pc = part + (size_t)n * C_OUT + 2 * lane;
    float vx = 0.f, vy = 0.f;
    #pragma unroll
    for (int cidx = 0; cidx < CC; ++cidx) {
        const float2 pp = *(const float2*)(pc + (size_t)cidx * N_PTS * C_OUT);
        vx += pp.x; vy += pp.y;
    }
    const float2 cb = *(const float2*)&conv_b[2 * lane];
    vx = fmaxf(vx + cb.x, 0.f);
    vy = fmaxf(vy + cb.y, 0.f);

    float logit[K_CLS];
    #pragma unroll
    for (int k = 0; k < K_CLS; ++k) {
        const float2 wv = *(const float2*)&fc_w[k * C_OUT + 2 * lane];
        float p = vx * wv.x + vy * wv.y;
        #pragma unroll
        for (int off = 32; off > 0; off >>= 1)
            p += __shfl_xor(p, off, 64);
        logit[k] = p + fc_b[k];
    }

    if (lane == 0) {
        float m = logit[0];
        #pragma unroll
        for (int k = 1; k < K_CLS; ++k) m = fmaxf(m, logit[k]);
        float e[K_CLS];
        float s = 0.f;
        #pragma unroll
        for (int k = 0; k < K_CLS; ++k) { e[k] = expf(logit[k] - m); s += e[k]; }
        const float inv  = 1.f / s;
        const float logs = logf(s);
        float lp = 0.f;
        #pragma unroll
        for (int k = 0; k < K_CLS; ++k) {
            P[n * K_CLS + k] = e[k] * inv;
            lp -= L[n * K_CLS + k] * ((logit[k] - m) - logs);
        }
        loss_part[n] = lp;
    }
}

// ---------------------------------------------------------------------------
// Kernel 3: deterministic loss reduction (one block, no atomics).
// ---------------------------------------------------------------------------
__global__ __launch_bounds__(512) void reduce_loss(
        const float* __restrict__ loss_part, float* __restrict__ out) {
    __shared__ float sh[N_PTS];
    const int t = threadIdx.x;
    sh[t] = loss_part[t];
    __syncthreads();
    for (int s = N_PTS / 2; s > 0; s >>= 1) {
        if (t < s) sh[t] += sh[t + s];
        __syncthreads();
    }
    if (t == 0) out[0] = sh[0];
}

// ---------------------------------------------------------------------------
extern "C" void kernel_launch(void* const* d_in, const int* in_sizes, int n_in,
                              void* d_out, int out_size, void* d_ws, size_t ws_size,
                              hipStream_t stream) {
    const float* bb      = (const float*)d_in[0];   // backbone_map
    const int*   centers = (const int*)  d_in[1];
    const float* L       = (const float*)d_in[2];
    const float* conv_w  = (const float*)d_in[3];
    const float* conv_b  = (const float*)d_in[4];
    const float* fc_w    = (const float*)d_in[5];
    const float* fc_b    = (const float*)d_in[6];

    float* out = (float*)d_out;            // P: [0, 2560), loss: [2560]

    // workspace (floats): part 8*512*128 (2.1 MB) + loss_part
    float* part      = (float*)d_ws;
    float* loss_part = part + (size_t)CC * N_PTS * C_OUT;

    gemm_conv<<<PTG_N * CC, 256, 0, stream>>>(bb, centers, conv_w, part);
    head_kernel<<<N_PTS, 64, 0, stream>>>(part, conv_b, fc_w, fc_b, L, out,
                                          loss_part);
    reduce_loss<<<1, N_PTS, 0, stream>>>(loss_part, out + N_PTS * K_CLS);
}